// Round 1
// baseline (1705.198 us; speedup 1.0000x reference)
//
#include <hip/hip_runtime.h>
#include <stdint.h>

#define N_TOK 4096
#define DIM   2048
#define VOCAB 50257
#define VPAD  50432   // 197 * 256
#define IGNORE_IDX (-100)

typedef short  bf16x8 __attribute__((ext_vector_type(8)));
typedef float  f32x4  __attribute__((ext_vector_type(4)));
typedef unsigned short u16x8 __attribute__((ext_vector_type(8)));

typedef const __attribute__((address_space(1))) unsigned int* gptr_t;
typedef __attribute__((address_space(3))) unsigned int*       lptr_t;

__device__ __forceinline__ unsigned short f2bf(float f) {
  union { float f; uint32_t u; } c; c.f = f;
  uint32_t u = c.u;
  return (unsigned short)((u + 0x7FFFu + ((u >> 16) & 1u)) >> 16);
}

// ---- fp32 -> bf16 conversion, weight padded to VPAD rows (pad = 0) ----
__global__ void cvt_weight(const float* __restrict__ w, unsigned short* __restrict__ o) {
  const int t   = blockIdx.x * 256 + threadIdx.x;
  const int idx = t << 3;                    // 8 elements per thread
  const int v   = idx >> 11;                 // / DIM
  u16x8 r = {0, 0, 0, 0, 0, 0, 0, 0};
  if (v < VOCAB) {
    const float4* p = (const float4*)(w + idx);
    const float4 x0 = p[0];
    const float4 x1 = p[1];
    r[0] = f2bf(x0.x); r[1] = f2bf(x0.y); r[2] = f2bf(x0.z); r[3] = f2bf(x0.w);
    r[4] = f2bf(x1.x); r[5] = f2bf(x1.y); r[6] = f2bf(x1.z); r[7] = f2bf(x1.w);
  }
  *(u16x8*)(o + idx) = r;
}

__global__ void cvt_input(const float* __restrict__ a, unsigned short* __restrict__ o) {
  const int t   = blockIdx.x * 256 + threadIdx.x;
  const int idx = t << 3;
  const float4* p = (const float4*)(a + idx);
  const float4 x0 = p[0];
  const float4 x1 = p[1];
  u16x8 r;
  r[0] = f2bf(x0.x); r[1] = f2bf(x0.y); r[2] = f2bf(x0.z); r[3] = f2bf(x0.w);
  r[4] = f2bf(x1.x); r[5] = f2bf(x1.y); r[6] = f2bf(x1.z); r[7] = f2bf(x1.w);
  *(u16x8*)(o + idx) = r;
}

// ============================================================================
// 256x256-tile 8-phase-template GEMM (T1+T2+T3/T4+T5), fused CE epilogue.
// C[m, v] = sum_k input[m,k] * weight[v,k]   (NT GEMM, both K-contiguous)
// 8 waves (2M x 4N), per-wave 128x64 output, BK=64, 4 phases per K-tile.
// LDS: 2 x (A 32KB + B 32KB) = 128 KiB double buffer.
// Swizzle: physical granule g (16B) holds logical granule g ^ (row&7); the
// same involution is applied on the global staging source (rule #21) and on
// the ds_read_b128 addresses -> conflict-free column-slice reads (T2).
// Counted vmcnt (T4): A-half of tile t+1 issued at iter top, B pairs inside
// phases 0/1; single s_waitcnt vmcnt(4) per K-tile, never 0 in main loop.
// ============================================================================

#define STAGE_A(nb, ko) do { \
  __builtin_amdgcn_global_load_lds((gptr_t)(const void*)(ag + 0 * 64 * DIM + (ko)), (lptr_t)(void*)(&As[nb][(0 * 512 + tid) * 8]), 16, 0, 0); \
  __builtin_amdgcn_global_load_lds((gptr_t)(const void*)(ag + 1 * 64 * DIM + (ko)), (lptr_t)(void*)(&As[nb][(1 * 512 + tid) * 8]), 16, 0, 0); \
  __builtin_amdgcn_global_load_lds((gptr_t)(const void*)(ag + 2 * 64 * DIM + (ko)), (lptr_t)(void*)(&As[nb][(2 * 512 + tid) * 8]), 16, 0, 0); \
  __builtin_amdgcn_global_load_lds((gptr_t)(const void*)(ag + 3 * 64 * DIM + (ko)), (lptr_t)(void*)(&As[nb][(3 * 512 + tid) * 8]), 16, 0, 0); \
} while (0)

#define STAGE_B0(nb, ko) do { \
  __builtin_amdgcn_global_load_lds((gptr_t)(const void*)(bg + 0 * 64 * DIM + (ko)), (lptr_t)(void*)(&Bs[nb][(0 * 512 + tid) * 8]), 16, 0, 0); \
  __builtin_amdgcn_global_load_lds((gptr_t)(const void*)(bg + 1 * 64 * DIM + (ko)), (lptr_t)(void*)(&Bs[nb][(1 * 512 + tid) * 8]), 16, 0, 0); \
} while (0)

#define STAGE_B1(nb, ko) do { \
  __builtin_amdgcn_global_load_lds((gptr_t)(const void*)(bg + 2 * 64 * DIM + (ko)), (lptr_t)(void*)(&Bs[nb][(2 * 512 + tid) * 8]), 16, 0, 0); \
  __builtin_amdgcn_global_load_lds((gptr_t)(const void*)(bg + 3 * 64 * DIM + (ko)), (lptr_t)(void*)(&Bs[nb][(3 * 512 + tid) * 8]), 16, 0, 0); \
} while (0)

#define LOAD_AV(mq) do { \
  _Pragma("unroll") \
  for (int fm = 0; fm < 4; ++fm) { \
    av[fm][0] = *(const bf16x8*)(Ab + ((mq) * 64 + fm * 16) * 64 + kx0); \
    av[fm][1] = *(const bf16x8*)(Ab + ((mq) * 64 + fm * 16) * 64 + kx1); \
  } \
} while (0)

#define LOAD_BV(nq) do { \
  _Pragma("unroll") \
  for (int fn = 0; fn < 2; ++fn) { \
    bv[nq][fn][0] = *(const bf16x8*)(Bb + ((nq) * 32 + fn * 16) * 64 + kx0); \
    bv[nq][fn][1] = *(const bf16x8*)(Bb + ((nq) * 32 + fn * 16) * 64 + kx1); \
  } \
} while (0)

#define MFMA16(mq, nq) do { \
  _Pragma("unroll") \
  for (int fm = 0; fm < 4; ++fm) \
    _Pragma("unroll") \
    for (int fn = 0; fn < 2; ++fn) { \
      acc[(mq) * 4 + fm][(nq) * 2 + fn] = __builtin_amdgcn_mfma_f32_16x16x32_bf16(av[fm][0], bv[nq][fn][0], acc[(mq) * 4 + fm][(nq) * 2 + fn], 0, 0, 0); \
      acc[(mq) * 4 + fm][(nq) * 2 + fn] = __builtin_amdgcn_mfma_f32_16x16x32_bf16(av[fm][1], bv[nq][fn][1], acc[(mq) * 4 + fm][(nq) * 2 + fn], 0, 0, 0); \
    } \
} while (0)

#define PHASE(mq, nq, DOA, DOB, STAGE_STMT) do { \
  if (DOA) LOAD_AV(mq); \
  if (DOB) LOAD_BV(nq); \
  STAGE_STMT; \
  __builtin_amdgcn_s_barrier(); \
  asm volatile("s_waitcnt lgkmcnt(0)" ::: "memory"); \
  __builtin_amdgcn_s_setprio(1); \
  MFMA16(mq, nq); \
  __builtin_amdgcn_s_setprio(0); \
  __builtin_amdgcn_s_barrier(); \
} while (0)

__global__ __launch_bounds__(512, 2) void flce_gemm(
    const unsigned short* __restrict__ A,   // [N_TOK][DIM]  bf16
    const unsigned short* __restrict__ B,   // [VPAD][DIM]   bf16
    const float* __restrict__ bias,         // [VOCAB]
    const int* __restrict__ target,         // [N_TOK]
    float* __restrict__ sumexp,             // [N_TOK] (pre-zeroed)
    float* __restrict__ tgtlog)             // [N_TOK]
{
  __shared__ unsigned short As[2][256 * 64];   // 64 KB
  __shared__ unsigned short Bs[2][256 * 64];   // 64 KB

  const int tid  = threadIdx.x;
  const int lane = tid & 63;
  const int wave = tid >> 6;
  const int wm   = wave >> 2;               // 0..1 -> 128 rows
  const int wn   = wave & 3;                // 0..3 -> 64 cols

  // T1: bijective XCD swizzle. nwg = 16*197 = 3152 = 8*394 exactly.
  // Consecutive swz on one XCD share v0 (B-panel L2 reuse).
  const int bid = blockIdx.x;
  const int swz = (bid & 7) * (3152 / 8) + (bid >> 3);
  const int m0  = (swz & 15) * 256;
  const int v0  = (swz >> 4) * 256;

  const int mrow = lane & 15;
  const int quad = lane >> 4;

  // ---- staging source (pre-swizzled global address, rule #21) ----
  // physical granule g = j*512 + tid; row = g>>3; logical col-granule
  // cg = (g ^ (g>>3)) & 7 = ((tid ^ (tid>>3)) & 7)  (j-independent).
  const int srow = tid >> 3;                       // + j*64 per load
  const int scg  = (tid ^ (tid >> 3)) & 7;
  const unsigned short* ag = A + (size_t)(m0 + srow) * DIM + scg * 8;
  const unsigned short* bg = B + (size_t)(v0 + srow) * DIM + scg * 8;

  // ---- ds_read swizzled k-offsets (bytes 4..6 XOR'd with row&7 == mrow&7) ----
  const int kx0 = (((0 * 64) + quad * 16) ^ ((mrow & 7) << 4)) >> 1;  // shorts
  const int kx1 = (((1 * 64) + quad * 16) ^ ((mrow & 7) << 4)) >> 1;

  f32x4 acc[8][4];
#pragma unroll
  for (int i = 0; i < 8; i++)
#pragma unroll
    for (int j = 0; j < 4; j++) acc[i][j] = (f32x4){0.f, 0.f, 0.f, 0.f};

  bf16x8 av[4][2];
  bf16x8 bv[2][2][2];

  // ---- prologue: stage tile 0 fully (issue order A x4, B0 x2, B1 x2) ----
  STAGE_A(0, 0);
  STAGE_B0(0, 0);
  STAGE_B1(0, 0);

  int cb = 0;
#pragma unroll 1
  for (int t = 0; t < 31; ++t) {
    const int nb = cb ^ 1;
    const int ko = (t + 1) * 64;            // shorts: 64 cols per K-tile
    STAGE_A(nb, ko);                        // tile t+1 A-halves (4 loads)
    // tile t fully landed (8 oldest); 4 A-loads of t+1 stay in flight.
    asm volatile("s_waitcnt vmcnt(4)" ::: "memory");
    __builtin_amdgcn_s_barrier();
    asm volatile("" ::: "memory");          // no ds_read hoists above this point
    const unsigned short* Ab = &As[cb][(wm * 128 + mrow) * 64];
    const unsigned short* Bb = &Bs[cb][(wn * 64 + mrow) * 64];
    PHASE(0, 0, 1, 1, STAGE_B0(nb, ko));
    PHASE(0, 1, 0, 1, STAGE_B1(nb, ko));
    PHASE(1, 0, 1, 0, (void)0);
    PHASE(1, 1, 0, 0, (void)0);
    cb = nb;
  }
  // ---- last K-tile (no prefetch; drain) ----
  asm volatile("s_waitcnt vmcnt(0)" ::: "memory");
  __builtin_amdgcn_s_barrier();
  asm volatile("" ::: "memory");
  {
    const unsigned short* Ab = &As[cb][(wm * 128 + mrow) * 64];
    const unsigned short* Bb = &Bs[cb][(wn * 64 + mrow) * 64];
    PHASE(0, 0, 1, 1, (void)0);
    PHASE(0, 1, 0, 1, (void)0);
    PHASE(1, 0, 1, 0, (void)0);
    PHASE(1, 1, 0, 0, (void)0);
  }

  // ---- epilogue: bias add, exp, per-row partial sums, target logit ----
  // C/D layout (verified m89): col = lane&15, row = (lane>>4)*4 + reg
  // acc[i][j]: rows m0 + wm*128 + i*16 + quad*4 + r ; cols v0 + wn*64 + j*16 + mrow
  const int colb = v0 + wn * 64;
#pragma unroll
  for (int i = 0; i < 8; ++i) {
    const int rowl = wm * 128 + i * 16 + quad * 4;
    const int4 tg = *(const int4*)(target + m0 + rowl);   // rows rowl..rowl+3
    float rs[4] = {0.f, 0.f, 0.f, 0.f};
#pragma unroll
    for (int j = 0; j < 4; ++j) {
      const int colg = colb + j * 16 + mrow;
      if (colg < VOCAB) {
        const float bvv = bias[colg];
#pragma unroll
        for (int r = 0; r < 4; ++r) {
          const float lg = acc[i][j][r] + bvv;
          rs[r] += __expf(lg);
          const int tgr = (r == 0) ? tg.x : (r == 1) ? tg.y : (r == 2) ? tg.z : tg.w;
          if (tgr == colg) tgtlog[m0 + rowl + r] = lg;
        }
      }
    }
#pragma unroll
    for (int r = 0; r < 4; ++r) {
      float v = rs[r];
      v += __shfl_xor(v, 1);
      v += __shfl_xor(v, 2);
      v += __shfl_xor(v, 4);
      v += __shfl_xor(v, 8);
      if (mrow == 0) atomicAdd(&sumexp[m0 + rowl + r], v);
    }
  }
}

// ---- final scalar reduction: loss and z_loss ----
__global__ void flce_final(const float* __restrict__ sumexp,
                           const float* __restrict__ tgtlog,
                           const int* __restrict__ target,
                           float* __restrict__ out) {
  const int tid = threadIdx.x;
  float ls = 0.f, zs = 0.f;
  int cnt = 0;
  for (int r = tid; r < N_TOK; r += 256) {
    const int t = target[r];
    if (t != IGNORE_IDX) {
      const float lse = logf(sumexp[r]);
      const float z = 1e-4f * lse * lse;
      ls += (lse - tgtlog[r]) + z;
      zs += z;
      cnt++;
    }
  }
#pragma unroll
  for (int off = 32; off > 0; off >>= 1) {
    ls += __shfl_down(ls, off);
    zs += __shfl_down(zs, off);
    cnt += __shfl_down(cnt, off);
  }
  __shared__ float sls[4], szs[4];
  __shared__ int scnt[4];
  const int lane = tid & 63, wv = tid >> 6;
  if (lane == 0) { sls[wv] = ls; szs[wv] = zs; scnt[wv] = cnt; }
  __syncthreads();
  if (tid == 0) {
    float L = 0.f, Z = 0.f;
    int C = 0;
    for (int w = 0; w < 4; w++) { L += sls[w]; Z += szs[w]; C += scnt[w]; }
    const float n = (float)(C > 0 ? C : 1);
    out[0] = L / n;
    out[1] = Z / n;
  }
}

extern "C" void kernel_launch(void* const* d_in, const int* in_sizes, int n_in,
                              void* d_out, int out_size, void* d_ws, size_t ws_size,
                              hipStream_t stream) {
  const float* input  = (const float*)d_in[0];
  const float* weight = (const float*)d_in[1];
  const float* bias   = (const float*)d_in[2];
  const int*   target = (const int*)d_in[3];
  float* out = (float*)d_out;

  unsigned short* wbf = (unsigned short*)d_ws;               // VPAD*DIM bf16
  unsigned short* abf = wbf + (size_t)VPAD * DIM;            // N_TOK*DIM bf16
  float* sumexp = (float*)(abf + (size_t)N_TOK * DIM);       // N_TOK f32
  float* tgtlog = sumexp + N_TOK;                            // N_TOK f32

  hipMemsetAsync(sumexp, 0, N_TOK * sizeof(float), stream);
  cvt_weight<<<(VPAD * DIM) / 2048, 256, 0, stream>>>(weight, wbf);
  cvt_input<<<(N_TOK * DIM) / 2048, 256, 0, stream>>>(input, abf);
  flce_gemm<<<(N_TOK / 256) * (VPAD / 256), 512, 0, stream>>>(abf, wbf, bias, target, sumexp, tgtlog);
  flce_final<<<1, 256, 0, stream>>>(sumexp, tgtlog, target, out);
}

// Round 2
// 1690.490 us; speedup vs baseline: 1.0087x; 1.0087x over previous
//
#include <hip/hip_runtime.h>
#include <stdint.h>

#define N_TOK 4096
#define DIM   2048
#define VOCAB 50257
#define VPAD  50432   // 197 * 256
#define IGNORE_IDX (-100)

typedef short  bf16x8 __attribute__((ext_vector_type(8)));
typedef float  f32x4  __attribute__((ext_vector_type(4)));
typedef unsigned short u16x8 __attribute__((ext_vector_type(8)));

typedef const __attribute__((address_space(1))) unsigned int* gptr_t;
typedef __attribute__((address_space(3))) unsigned int*       lptr_t;

__device__ __forceinline__ unsigned short f2bf(float f) {
  union { float f; uint32_t u; } c; c.f = f;
  uint32_t u = c.u;
  return (unsigned short)((u + 0x7FFFu + ((u >> 16) & 1u)) >> 16);
}

// ---- fp32 -> bf16 conversion, weight padded to VPAD rows (pad = 0) ----
__global__ void cvt_weight(const float* __restrict__ w, unsigned short* __restrict__ o) {
  const int t   = blockIdx.x * 256 + threadIdx.x;
  const int idx = t << 3;                    // 8 elements per thread
  const int v   = idx >> 11;                 // / DIM
  u16x8 r = {0, 0, 0, 0, 0, 0, 0, 0};
  if (v < VOCAB) {
    const float4* p = (const float4*)(w + idx);
    const float4 x0 = p[0];
    const float4 x1 = p[1];
    r[0] = f2bf(x0.x); r[1] = f2bf(x0.y); r[2] = f2bf(x0.z); r[3] = f2bf(x0.w);
    r[4] = f2bf(x1.x); r[5] = f2bf(x1.y); r[6] = f2bf(x1.z); r[7] = f2bf(x1.w);
  }
  *(u16x8*)(o + idx) = r;
}

__global__ void cvt_input(const float* __restrict__ a, unsigned short* __restrict__ o) {
  const int t   = blockIdx.x * 256 + threadIdx.x;
  const int idx = t << 3;
  const float4* p = (const float4*)(a + idx);
  const float4 x0 = p[0];
  const float4 x1 = p[1];
  u16x8 r;
  r[0] = f2bf(x0.x); r[1] = f2bf(x0.y); r[2] = f2bf(x0.z); r[3] = f2bf(x0.w);
  r[4] = f2bf(x1.x); r[5] = f2bf(x1.y); r[6] = f2bf(x1.z); r[7] = f2bf(x1.w);
  *(u16x8*)(o + idx) = r;
}

// ============================================================================
// 256x256-tile GEMM, 8 waves (2M x 4N), BK=64, fused CE epilogue.
// R1 schedule: ALL 8 global_load_lds of tile t+1 issued at top of iter t
// (buffer nb free since tile t-1's reads completed before iter t-1's last
// barrier). Counted s_waitcnt vmcnt(8) -> full-K-tile prefetch slack, never
// drains to 0 in the main loop. One barrier per phase (reads -> barrier ->
// MFMA); compiler emits fine-grained lgkmcnt waits before MFMA operand use,
// which also guarantees all reads of a buffer complete before the next
// barrier (staging-overwrite safety). Read distribution 12/4/8/0 across the
// 4 quadrant phases; setprio(1) brackets each 16-MFMA cluster (T5).
// LDS XOR-swizzle (T2) unchanged: 0 bank conflicts measured in R1.
// ============================================================================

#define STAGE_ALL(nb, ko) do { \
  __builtin_amdgcn_global_load_lds((gptr_t)(const void*)(ag + 0 * 64 * DIM + (ko)), (lptr_t)(void*)(&As[nb][(0 * 512 + tid) * 8]), 16, 0, 0); \
  __builtin_amdgcn_global_load_lds((gptr_t)(const void*)(ag + 1 * 64 * DIM + (ko)), (lptr_t)(void*)(&As[nb][(1 * 512 + tid) * 8]), 16, 0, 0); \
  __builtin_amdgcn_global_load_lds((gptr_t)(const void*)(ag + 2 * 64 * DIM + (ko)), (lptr_t)(void*)(&As[nb][(2 * 512 + tid) * 8]), 16, 0, 0); \
  __builtin_amdgcn_global_load_lds((gptr_t)(const void*)(ag + 3 * 64 * DIM + (ko)), (lptr_t)(void*)(&As[nb][(3 * 512 + tid) * 8]), 16, 0, 0); \
  __builtin_amdgcn_global_load_lds((gptr_t)(const void*)(bg + 0 * 64 * DIM + (ko)), (lptr_t)(void*)(&Bs[nb][(0 * 512 + tid) * 8]), 16, 0, 0); \
  __builtin_amdgcn_global_load_lds((gptr_t)(const void*)(bg + 1 * 64 * DIM + (ko)), (lptr_t)(void*)(&Bs[nb][(1 * 512 + tid) * 8]), 16, 0, 0); \
  __builtin_amdgcn_global_load_lds((gptr_t)(const void*)(bg + 2 * 64 * DIM + (ko)), (lptr_t)(void*)(&Bs[nb][(2 * 512 + tid) * 8]), 16, 0, 0); \
  __builtin_amdgcn_global_load_lds((gptr_t)(const void*)(bg + 3 * 64 * DIM + (ko)), (lptr_t)(void*)(&Bs[nb][(3 * 512 + tid) * 8]), 16, 0, 0); \
} while (0)

#define LOAD_AV(mq) do { \
  _Pragma("unroll") \
  for (int fm = 0; fm < 4; ++fm) { \
    av[fm][0] = *(const bf16x8*)(Ab + ((mq) * 64 + fm * 16) * 64 + kx0); \
    av[fm][1] = *(const bf16x8*)(Ab + ((mq) * 64 + fm * 16) * 64 + kx1); \
  } \
} while (0)

#define LOAD_BV(nq) do { \
  _Pragma("unroll") \
  for (int fn = 0; fn < 2; ++fn) { \
    bv[nq][fn][0] = *(const bf16x8*)(Bb + ((nq) * 32 + fn * 16) * 64 + kx0); \
    bv[nq][fn][1] = *(const bf16x8*)(Bb + ((nq) * 32 + fn * 16) * 64 + kx1); \
  } \
} while (0)

#define MFMA16(mq, nq) do { \
  _Pragma("unroll") \
  for (int fm = 0; fm < 4; ++fm) \
    _Pragma("unroll") \
    for (int fn = 0; fn < 2; ++fn) { \
      acc[(mq) * 4 + fm][(nq) * 2 + fn] = __builtin_amdgcn_mfma_f32_16x16x32_bf16(av[fm][0], bv[nq][fn][0], acc[(mq) * 4 + fm][(nq) * 2 + fn], 0, 0, 0); \
      acc[(mq) * 4 + fm][(nq) * 2 + fn] = __builtin_amdgcn_mfma_f32_16x16x32_bf16(av[fm][1], bv[nq][fn][1], acc[(mq) * 4 + fm][(nq) * 2 + fn], 0, 0, 0); \
    } \
} while (0)

#define MFMA_PHASE(mq, nq) do { \
  __builtin_amdgcn_s_barrier(); \
  __builtin_amdgcn_s_setprio(1); \
  MFMA16(mq, nq); \
  __builtin_amdgcn_s_setprio(0); \
} while (0)

__global__ __launch_bounds__(512, 2) void flce_gemm(
    const unsigned short* __restrict__ A,   // [N_TOK][DIM]  bf16
    const unsigned short* __restrict__ B,   // [VPAD][DIM]   bf16
    const float* __restrict__ bias,         // [VOCAB]
    const int* __restrict__ target,         // [N_TOK]
    float* __restrict__ sumexp,             // [N_TOK] (pre-zeroed)
    float* __restrict__ tgtlog)             // [N_TOK]
{
  __shared__ unsigned short As[2][256 * 64];   // 64 KB
  __shared__ unsigned short Bs[2][256 * 64];   // 64 KB

  const int tid  = threadIdx.x;
  const int lane = tid & 63;
  const int wave = tid >> 6;
  const int wm   = wave >> 2;               // 0..1 -> 128 rows
  const int wn   = wave & 3;                // 0..3 -> 64 cols

  // T1: bijective XCD swizzle. nwg = 16*197 = 3152 = 8*394 exactly.
  const int bid = blockIdx.x;
  const int swz = (bid & 7) * (3152 / 8) + (bid >> 3);
  const int m0  = (swz & 15) * 256;
  const int v0  = (swz >> 4) * 256;

  const int mrow = lane & 15;
  const int quad = lane >> 4;

  // ---- staging source (pre-swizzled global address, rule #21) ----
  // physical granule g = j*512 + tid; row = g>>3; logical col-granule
  // cg = (g ^ (g>>3)) & 7 = ((tid ^ (tid>>3)) & 7)  (j-independent).
  const int srow = tid >> 3;                       // + j*64 per load
  const int scg  = (tid ^ (tid >> 3)) & 7;
  const unsigned short* ag = A + (size_t)(m0 + srow) * DIM + scg * 8;
  const unsigned short* bg = B + (size_t)(v0 + srow) * DIM + scg * 8;

  // ---- ds_read swizzled k-offsets (byte bits 4..6 XOR'd with row&7) ----
  const int kx0 = (((0 * 64) + quad * 16) ^ ((mrow & 7) << 4)) >> 1;  // shorts
  const int kx1 = (((1 * 64) + quad * 16) ^ ((mrow & 7) << 4)) >> 1;

  f32x4 acc[8][4];
#pragma unroll
  for (int i = 0; i < 8; i++)
#pragma unroll
    for (int j = 0; j < 4; j++) acc[i][j] = (f32x4){0.f, 0.f, 0.f, 0.f};

  bf16x8 av[4][2];
  bf16x8 bv[2][2][2];

  // ---- prologue: stage tile 0 ----
  STAGE_ALL(0, 0);

  int cb = 0;
#pragma unroll 1
  for (int t = 0; t < 32; ++t) {
    const int nb = cb ^ 1;
    if (t < 31) {
      STAGE_ALL(nb, (t + 1) * 64);          // tile t+1: full K-tile of slack
      asm volatile("s_waitcnt vmcnt(8)" ::: "memory");  // tile t landed; 8 in flight
    } else {
      asm volatile("s_waitcnt vmcnt(0)" ::: "memory");  // drain for last tile
    }
    __builtin_amdgcn_s_barrier();           // all waves see staged tile t
    asm volatile("" ::: "memory");          // no ds_read hoists above this point

    const unsigned short* Ab = &As[cb][(wm * 128 + mrow) * 64];
    const unsigned short* Bb = &Bs[cb][(wn * 64 + mrow) * 64];

    LOAD_AV(0);                              // 8 reads
    LOAD_BV(0);                              // 4 reads
    MFMA_PHASE(0, 0);
    LOAD_BV(1);                              // 4 reads (overlaps phase-0 skew)
    MFMA_PHASE(0, 1);
    LOAD_AV(1);                              // 8 reads (after last av-as-A0 use)
    MFMA_PHASE(1, 0);
    MFMA_PHASE(1, 1);

    cb = nb;
  }

  // ---- epilogue: bias add, exp, per-row partial sums, target logit ----
  // C/D layout (verified m89): col = lane&15, row = (lane>>4)*4 + reg
  // acc[i][j]: rows m0 + wm*128 + i*16 + quad*4 + r ; cols v0 + wn*64 + j*16 + mrow
  const int colb = v0 + wn * 64;
#pragma unroll
  for (int i = 0; i < 8; ++i) {
    const int rowl = wm * 128 + i * 16 + quad * 4;
    const int4 tg = *(const int4*)(target + m0 + rowl);   // rows rowl..rowl+3
    float rs[4] = {0.f, 0.f, 0.f, 0.f};
#pragma unroll
    for (int j = 0; j < 4; ++j) {
      const int colg = colb + j * 16 + mrow;
      if (colg < VOCAB) {
        const float bvv = bias[colg];
#pragma unroll
        for (int r = 0; r < 4; ++r) {
          const float lg = acc[i][j][r] + bvv;
          rs[r] += __expf(lg);
          const int tgr = (r == 0) ? tg.x : (r == 1) ? tg.y : (r == 2) ? tg.z : tg.w;
          if (tgr == colg) tgtlog[m0 + rowl + r] = lg;
        }
      }
    }
#pragma unroll
    for (int r = 0; r < 4; ++r) {
      float v = rs[r];
      v += __shfl_xor(v, 1);
      v += __shfl_xor(v, 2);
      v += __shfl_xor(v, 4);
      v += __shfl_xor(v, 8);
      if (mrow == 0) atomicAdd(&sumexp[m0 + rowl + r], v);
    }
  }
}

// ---- final scalar reduction: loss and z_loss ----
__global__ void flce_final(const float* __restrict__ sumexp,
                           const float* __restrict__ tgtlog,
                           const int* __restrict__ target,
                           float* __restrict__ out) {
  const int tid = threadIdx.x;
  float ls = 0.f, zs = 0.f;
  int cnt = 0;
  for (int r = tid; r < N_TOK; r += 256) {
    const int t = target[r];
    if (t != IGNORE_IDX) {
      const float lse = logf(sumexp[r]);
      const float z = 1e-4f * lse * lse;
      ls += (lse - tgtlog[r]) + z;
      zs += z;
      cnt++;
    }
  }
#pragma unroll
  for (int off = 32; off > 0; off >>= 1) {
    ls += __shfl_down(ls, off);
    zs += __shfl_down(zs, off);
    cnt += __shfl_down(cnt, off);
  }
  __shared__ float sls[4], szs[4];
  __shared__ int scnt[4];
  const int lane = tid & 63, wv = tid >> 6;
  if (lane == 0) { sls[wv] = ls; szs[wv] = zs; scnt[wv] = cnt; }
  __syncthreads();
  if (tid == 0) {
    float L = 0.f, Z = 0.f;
    int C = 0;
    for (int w = 0; w < 4; w++) { L += sls[w]; Z += szs[w]; C += scnt[w]; }
    const float n = (float)(C > 0 ? C : 1);
    out[0] = L / n;
    out[1] = Z / n;
  }
}

extern "C" void kernel_launch(void* const* d_in, const int* in_sizes, int n_in,
                              void* d_out, int out_size, void* d_ws, size_t ws_size,
                              hipStream_t stream) {
  const float* input  = (const float*)d_in[0];
  const float* weight = (const float*)d_in[1];
  const float* bias   = (const float*)d_in[2];
  const int*   target = (const int*)d_in[3];
  float* out = (float*)d_out;

  unsigned short* wbf = (unsigned short*)d_ws;               // VPAD*DIM bf16
  unsigned short* abf = wbf + (size_t)VPAD * DIM;            // N_TOK*DIM bf16
  float* sumexp = (float*)(abf + (size_t)N_TOK * DIM);       // N_TOK f32
  float* tgtlog = sumexp + N_TOK;                            // N_TOK f32

  hipMemsetAsync(sumexp, 0, N_TOK * sizeof(float), stream);
  cvt_weight<<<(VPAD * DIM) / 2048, 256, 0, stream>>>(weight, wbf);
  cvt_input<<<(N_TOK * DIM) / 2048, 256, 0, stream>>>(input, abf);
  flce_gemm<<<(N_TOK / 256) * (VPAD / 256), 512, 0, stream>>>(abf, wbf, bias, target, sumexp, tgtlog);
  flce_final<<<1, 256, 0, stream>>>(sumexp, tgtlog, target, out);
}

// Round 5
// 1547.779 us; speedup vs baseline: 1.1017x; 1.0922x over previous
//
#include <hip/hip_runtime.h>
#include <stdint.h>

#define N_TOK 4096
#define DIM   2048
#define VOCAB 50257
#define VPAD  50432   // 197 * 256
#define IGNORE_IDX (-100)

typedef short  bf16x8 __attribute__((ext_vector_type(8)));
typedef float  f32x4  __attribute__((ext_vector_type(4)));
typedef unsigned short u16x8 __attribute__((ext_vector_type(8)));

typedef const __attribute__((address_space(1))) unsigned int* gptr_t;
typedef __attribute__((address_space(3))) unsigned int*       lptr_t;

__device__ __forceinline__ unsigned short f2bf(float f) {
  union { float f; uint32_t u; } c; c.f = f;
  uint32_t u = c.u;
  return (unsigned short)((u + 0x7FFFu + ((u >> 16) & 1u)) >> 16);
}

// ---- fp32 -> bf16 conversion, weight padded to VPAD rows (pad = 0) ----
__global__ void cvt_weight(const float* __restrict__ w, unsigned short* __restrict__ o) {
  const int t   = blockIdx.x * 256 + threadIdx.x;
  const int idx = t << 3;                    // 8 elements per thread
  const int v   = idx >> 11;                 // / DIM
  u16x8 r = {0, 0, 0, 0, 0, 0, 0, 0};
  if (v < VOCAB) {
    const float4* p = (const float4*)(w + idx);
    const float4 x0 = p[0];
    const float4 x1 = p[1];
    r[0] = f2bf(x0.x); r[1] = f2bf(x0.y); r[2] = f2bf(x0.z); r[3] = f2bf(x0.w);
    r[4] = f2bf(x1.x); r[5] = f2bf(x1.y); r[6] = f2bf(x1.z); r[7] = f2bf(x1.w);
  }
  *(u16x8*)(o + idx) = r;
}

__global__ void cvt_input(const float* __restrict__ a, unsigned short* __restrict__ o) {
  const int t   = blockIdx.x * 256 + threadIdx.x;
  const int idx = t << 3;
  const float4* p = (const float4*)(a + idx);
  const float4 x0 = p[0];
  const float4 x1 = p[1];
  u16x8 r;
  r[0] = f2bf(x0.x); r[1] = f2bf(x0.y); r[2] = f2bf(x0.z); r[3] = f2bf(x0.w);
  r[4] = f2bf(x1.x); r[5] = f2bf(x1.y); r[6] = f2bf(x1.z); r[7] = f2bf(x1.w);
  *(u16x8*)(o + idx) = r;
}

// ============================================================================
// 256x256-tile GEMM, 8 waves (2M x 4N), BK=64, fused CE epilogue.
// R3 experiment (resubmitted; two infra failures, never measured):
// STATICALLY DISJOINT double buffers (As0/Bs0/As1/Bs1 as four separate
// __shared__ objects) + K-loop unrolled by 2 so the buffer is a compile-time
// object. Rationale: with As[2][..] and runtime cb, alias analysis cannot
// prove ds_read(buf cb) independent of global_load_lds DMA writes (buf cb^1),
// so the compiler inserts conservative vmcnt waits that kill the counted-
// vmcnt pipeline (R1->R2 schedule changes were both null: the stall is
// schedule-invariant). Distinct objects remove the inferred dependency;
// asm vmcnt(8) is then the only VMEM wait in the loop. Everything else
// (T1 XCD swizzle, T2 XOR-swizzle w/ pre-swizzled source, 4 phase barriers
// + setprio) unchanged from the R2-verified kernel (absmax 0.0).
// ============================================================================

#define STAGE(AD, BD, ko) do { \
  __builtin_amdgcn_global_load_lds((gptr_t)(const void*)(ag + 0 * 64 * DIM + (ko)), (lptr_t)(void*)(&AD[(0 * 512 + tid) * 8]), 16, 0, 0); \
  __builtin_amdgcn_global_load_lds((gptr_t)(const void*)(ag + 1 * 64 * DIM + (ko)), (lptr_t)(void*)(&AD[(1 * 512 + tid) * 8]), 16, 0, 0); \
  __builtin_amdgcn_global_load_lds((gptr_t)(const void*)(ag + 2 * 64 * DIM + (ko)), (lptr_t)(void*)(&AD[(2 * 512 + tid) * 8]), 16, 0, 0); \
  __builtin_amdgcn_global_load_lds((gptr_t)(const void*)(ag + 3 * 64 * DIM + (ko)), (lptr_t)(void*)(&AD[(3 * 512 + tid) * 8]), 16, 0, 0); \
  __builtin_amdgcn_global_load_lds((gptr_t)(const void*)(bg + 0 * 64 * DIM + (ko)), (lptr_t)(void*)(&BD[(0 * 512 + tid) * 8]), 16, 0, 0); \
  __builtin_amdgcn_global_load_lds((gptr_t)(const void*)(bg + 1 * 64 * DIM + (ko)), (lptr_t)(void*)(&BD[(1 * 512 + tid) * 8]), 16, 0, 0); \
  __builtin_amdgcn_global_load_lds((gptr_t)(const void*)(bg + 2 * 64 * DIM + (ko)), (lptr_t)(void*)(&BD[(2 * 512 + tid) * 8]), 16, 0, 0); \
  __builtin_amdgcn_global_load_lds((gptr_t)(const void*)(bg + 3 * 64 * DIM + (ko)), (lptr_t)(void*)(&BD[(3 * 512 + tid) * 8]), 16, 0, 0); \
} while (0)

#define LOAD_AV(mq) do { \
  _Pragma("unroll") \
  for (int fm = 0; fm < 4; ++fm) { \
    av[fm][0] = *(const bf16x8*)(Ab + ((mq) * 64 + fm * 16) * 64 + kx0); \
    av[fm][1] = *(const bf16x8*)(Ab + ((mq) * 64 + fm * 16) * 64 + kx1); \
  } \
} while (0)

#define LOAD_BV(nq) do { \
  _Pragma("unroll") \
  for (int fn = 0; fn < 2; ++fn) { \
    bv[nq][fn][0] = *(const bf16x8*)(Bb + ((nq) * 32 + fn * 16) * 64 + kx0); \
    bv[nq][fn][1] = *(const bf16x8*)(Bb + ((nq) * 32 + fn * 16) * 64 + kx1); \
  } \
} while (0)

#define MFMA16(mq, nq) do { \
  _Pragma("unroll") \
  for (int fm = 0; fm < 4; ++fm) \
    _Pragma("unroll") \
    for (int fn = 0; fn < 2; ++fn) { \
      acc[(mq) * 4 + fm][(nq) * 2 + fn] = __builtin_amdgcn_mfma_f32_16x16x32_bf16(av[fm][0], bv[nq][fn][0], acc[(mq) * 4 + fm][(nq) * 2 + fn], 0, 0, 0); \
      acc[(mq) * 4 + fm][(nq) * 2 + fn] = __builtin_amdgcn_mfma_f32_16x16x32_bf16(av[fm][1], bv[nq][fn][1], acc[(mq) * 4 + fm][(nq) * 2 + fn], 0, 0, 0); \
    } \
} while (0)

#define MFMA_PHASE(mq, nq) do { \
  __builtin_amdgcn_s_barrier(); \
  __builtin_amdgcn_s_setprio(1); \
  MFMA16(mq, nq); \
  __builtin_amdgcn_s_setprio(0); \
} while (0)

// per-K-tile compute body on a given (compile-time) buffer pair
#define KTILE(AS, BS) do { \
  const unsigned short* Ab = &AS[(wm * 128 + mrow) * 64]; \
  const unsigned short* Bb = &BS[(wn * 64 + mrow) * 64]; \
  LOAD_AV(0);                              /* 8 reads  */ \
  LOAD_BV(0);                              /* 4 reads  */ \
  MFMA_PHASE(0, 0); \
  LOAD_BV(1);                              /* 4 reads  */ \
  MFMA_PHASE(0, 1); \
  LOAD_AV(1);                              /* 8 reads  */ \
  MFMA_PHASE(1, 0); \
  MFMA_PHASE(1, 1); \
} while (0)

__global__ __launch_bounds__(512, 2) void flce_gemm(
    const unsigned short* __restrict__ A,   // [N_TOK][DIM]  bf16
    const unsigned short* __restrict__ B,   // [VPAD][DIM]   bf16
    const float* __restrict__ bias,         // [VOCAB]
    const int* __restrict__ target,         // [N_TOK]
    float* __restrict__ sumexp,             // [N_TOK] (pre-zeroed)
    float* __restrict__ tgtlog)             // [N_TOK]
{
  // four statically-disjoint staging buffers (2 x 32 KB per matrix)
  __shared__ unsigned short As0[256 * 64];
  __shared__ unsigned short Bs0[256 * 64];
  __shared__ unsigned short As1[256 * 64];
  __shared__ unsigned short Bs1[256 * 64];

  const int tid  = threadIdx.x;
  const int lane = tid & 63;
  const int wave = tid >> 6;
  const int wm   = wave >> 2;               // 0..1 -> 128 rows
  const int wn   = wave & 3;                // 0..3 -> 64 cols

  // T1: bijective XCD swizzle. nwg = 16*197 = 3152 = 8*394 exactly.
  const int bid = blockIdx.x;
  const int swz = (bid & 7) * (3152 / 8) + (bid >> 3);
  const int m0  = (swz & 15) * 256;
  const int v0  = (swz >> 4) * 256;

  const int mrow = lane & 15;
  const int quad = lane >> 4;

  // ---- staging source (pre-swizzled global address, rule #21) ----
  // physical granule g = j*512 + tid; row = g>>3; logical col-granule
  // cg = (g ^ (g>>3)) & 7 = ((tid ^ (tid>>3)) & 7)  (j-independent).
  const int srow = tid >> 3;                       // + j*64 per load
  const int scg  = (tid ^ (tid >> 3)) & 7;
  const unsigned short* ag = A + (size_t)(m0 + srow) * DIM + scg * 8;
  const unsigned short* bg = B + (size_t)(v0 + srow) * DIM + scg * 8;

  // ---- ds_read swizzled k-offsets (byte bits 4..6 XOR'd with row&7) ----
  const int kx0 = (((0 * 64) + quad * 16) ^ ((mrow & 7) << 4)) >> 1;  // shorts
  const int kx1 = (((1 * 64) + quad * 16) ^ ((mrow & 7) << 4)) >> 1;

  f32x4 acc[8][4];
#pragma unroll
  for (int i = 0; i < 8; i++)
#pragma unroll
    for (int j = 0; j < 4; j++) acc[i][j] = (f32x4){0.f, 0.f, 0.f, 0.f};

  bf16x8 av[4][2];
  bf16x8 bv[2][2][2];

  // ---- prologue: stage K-tile 0 into buf0 ----
  STAGE(As0, Bs0, 0);

#pragma unroll 1
  for (int t = 0; t < 16; ++t) {
    // ---- even K-tile 2t: compute buf0, prefetch K-tile 2t+1 -> buf1 ----
    STAGE(As1, Bs1, (2 * t + 1) * 64);
    asm volatile("s_waitcnt vmcnt(8)" ::: "memory");   // tile 2t landed; 8 in flight
    __builtin_amdgcn_s_barrier();
    asm volatile("" ::: "memory");
    KTILE(As0, Bs0);

    // ---- odd K-tile 2t+1: compute buf1, prefetch K-tile 2t+2 -> buf0 ----
    if (t < 15) {
      STAGE(As0, Bs0, (2 * t + 2) * 64);
      asm volatile("s_waitcnt vmcnt(8)" ::: "memory");
    } else {
      asm volatile("s_waitcnt vmcnt(0)" ::: "memory"); // last tile: drain
    }
    __builtin_amdgcn_s_barrier();
    asm volatile("" ::: "memory");
    KTILE(As1, Bs1);
  }

  // ---- epilogue: bias add, exp, per-row partial sums, target logit ----
  // C/D layout (verified m89): col = lane&15, row = (lane>>4)*4 + reg
  // acc[i][j]: rows m0 + wm*128 + i*16 + quad*4 + r ; cols v0 + wn*64 + j*16 + mrow
  const int colb = v0 + wn * 64;
#pragma unroll
  for (int i = 0; i < 8; ++i) {
    const int rowl = wm * 128 + i * 16 + quad * 4;
    const int4 tg = *(const int4*)(target + m0 + rowl);   // rows rowl..rowl+3
    float rs[4] = {0.f, 0.f, 0.f, 0.f};
#pragma unroll
    for (int j = 0; j < 4; ++j) {
      const int colg = colb + j * 16 + mrow;
      if (colg < VOCAB) {
        const float bvv = bias[colg];
#pragma unroll
        for (int r = 0; r < 4; ++r) {
          const float lg = acc[i][j][r] + bvv;
          rs[r] += __expf(lg);
          const int tgr = (r == 0) ? tg.x : (r == 1) ? tg.y : (r == 2) ? tg.z : tg.w;
          if (tgr == colg) tgtlog[m0 + rowl + r] = lg;
        }
      }
    }
#pragma unroll
    for (int r = 0; r < 4; ++r) {
      float v = rs[r];
      v += __shfl_xor(v, 1);
      v += __shfl_xor(v, 2);
      v += __shfl_xor(v, 4);
      v += __shfl_xor(v, 8);
      if (mrow == 0) atomicAdd(&sumexp[m0 + rowl + r], v);
    }
  }
}

// ---- final scalar reduction: loss and z_loss ----
__global__ void flce_final(const float* __restrict__ sumexp,
                           const float* __restrict__ tgtlog,
                           const int* __restrict__ target,
                           float* __restrict__ out) {
  const int tid = threadIdx.x;
  float ls = 0.f, zs = 0.f;
  int cnt = 0;
  for (int r = tid; r < N_TOK; r += 256) {
    const int t = target[r];
    if (t != IGNORE_IDX) {
      const float lse = logf(sumexp[r]);
      const float z = 1e-4f * lse * lse;
      ls += (lse - tgtlog[r]) + z;
      zs += z;
      cnt++;
    }
  }
#pragma unroll
  for (int off = 32; off > 0; off >>= 1) {
    ls += __shfl_down(ls, off);
    zs += __shfl_down(zs, off);
    cnt += __shfl_down(cnt, off);
  }
  __shared__ float sls[4], szs[4];
  __shared__ int scnt[4];
  const int lane = tid & 63, wv = tid >> 6;
  if (lane == 0) { sls[wv] = ls; szs[wv] = zs; scnt[wv] = cnt; }
  __syncthreads();
  if (tid == 0) {
    float L = 0.f, Z = 0.f;
    int C = 0;
    for (int w = 0; w < 4; w++) { L += sls[w]; Z += szs[w]; C += scnt[w]; }
    const float n = (float)(C > 0 ? C : 1);
    out[0] = L / n;
    out[1] = Z / n;
  }
}

extern "C" void kernel_launch(void* const* d_in, const int* in_sizes, int n_in,
                              void* d_out, int out_size, void* d_ws, size_t ws_size,
                              hipStream_t stream) {
  const float* input  = (const float*)d_in[0];
  const float* weight = (const float*)d_in[1];
  const float* bias   = (const float*)d_in[2];
  const int*   target = (const int*)d_in[3];
  float* out = (float*)d_out;

  unsigned short* wbf = (unsigned short*)d_ws;               // VPAD*DIM bf16
  unsigned short* abf = wbf + (size_t)VPAD * DIM;            // N_TOK*DIM bf16
  float* sumexp = (float*)(abf + (size_t)N_TOK * DIM);       // N_TOK f32
  float* tgtlog = sumexp + N_TOK;                            // N_TOK f32

  hipMemsetAsync(sumexp, 0, N_TOK * sizeof(float), stream);
  cvt_weight<<<(VPAD * DIM) / 2048, 256, 0, stream>>>(weight, wbf);
  cvt_input<<<(N_TOK * DIM) / 2048, 256, 0, stream>>>(input, abf);
  flce_gemm<<<(N_TOK / 256) * (VPAD / 256), 512, 0, stream>>>(abf, wbf, bias, target, sumexp, tgtlog);
  flce_final<<<1, 256, 0, stream>>>(sumexp, tgtlog, target, out);
}